// Round 15
// baseline (189.652 us; speedup 1.0000x reference)
//
#include <hip/hip_runtime.h>
#include <hip/hip_bf16.h>

#define NROW 8192
#define DDIM 512
#define MARGIN 0.2f

typedef __bf16 bf16x8 __attribute__((ext_vector_type(8)));
typedef float f32x4 __attribute__((ext_vector_type(4)));

__device__ __forceinline__ void gload16(const void* g, void* l) {
    __builtin_amdgcn_global_load_lds(
        (const __attribute__((address_space(1))) void*)g,
        (__attribute__((address_space(3))) void*)l, 16, 0, 0);
}

#define BAR() __builtin_amdgcn_s_barrier()

// ---------------------------------------------------------------------------
// prep: blocks 0..N-1 handle im (convert + idat={||im||^2, MARGIN+||im-s||}),
//       N..2N-1 handle ex (convert + ||ex||^2)
// ---------------------------------------------------------------------------
__global__ __launch_bounds__(256) void prep_kernel(
    const float* __restrict__ im, const float* __restrict__ s,
    const float* __restrict__ ex,
    ushort* __restrict__ Abf, ushort* __restrict__ Bbf,
    float2* __restrict__ idat, float* __restrict__ exsq) {
    int b = blockIdx.x;
    bool isim = b < NROW;
    int row = isim ? b : b - NROW;
    const float* src = isim ? im : ex;
    ushort* dst = isim ? Abf : Bbf;
    int tid = threadIdx.x;

    float2 v = ((const float2*)(src + (size_t)row * DDIM))[tid];
    __hip_bfloat16 hx = __float2bfloat16(v.x);
    __hip_bfloat16 hy = __float2bfloat16(v.y);
    unsigned packed = (unsigned)*(const ushort*)&hx | ((unsigned)*(const ushort*)&hy << 16);
    ((unsigned*)(dst + (size_t)row * DDIM))[tid] = packed;

    float ssq = v.x * v.x + v.y * v.y;
    float dsq = 0.f;
    if (isim) {
        float2 sv = ((const float2*)(s + (size_t)row * DDIM))[tid];
        float dx = v.x - sv.x, dy = v.y - sv.y;
        dsq = dx * dx + dy * dy;
    }
    #pragma unroll
    for (int off = 32; off > 0; off >>= 1) {
        ssq += __shfl_down(ssq, off);
        dsq += __shfl_down(dsq, off);
    }
    __shared__ float sred[8];
    int lane = tid & 63, w = tid >> 6;
    if (lane == 0) { sred[w] = ssq; sred[4 + w] = dsq; }
    __syncthreads();
    if (tid == 0) {
        float S = sred[0] + sred[1] + sred[2] + sred[3];
        float Dd = sred[4] + sred[5] + sred[6] + sred[7];
        if (isim) idat[row] = make_float2(S, MARGIN + sqrtf(Dd));
        else      exsq[row] = S;
    }
}

// ---------------------------------------------------------------------------
// 128x128 GEMM + fused epilogue. 4 waves (2x2), BK=64, 2 blocks/CU.
// KEY CHANGE vs round 14: B operands come DIRECTLY FROM GLOBAL (L2) into a
// register double-buffer -- B never touches LDS. Evidence: R12 proved the
// MFMA+barrier skeleton runs at full rate; 5 schedules all pinned at 19-24%
// MfmaUtil because ALL operands funneled through the single per-CU LDS pipe
// (reads + staging writes ~2700 cyc/K-tile, serialized against MFMA by the
// read->barrier->MFMA structure). Removing B halves LDS read traffic and
// staging, and B's latency is hidden by a 1-tile register pipeline with no
// block synchronization.
// A stays in LDS (shared by both wc-waves), dbuf 2x16KB, chunk16 XOR swizzle
// phys = logical ^ (row&7) on both sides. A half-tiles h = 2*kt + q (8KB).
// Ledger per iter t: [a-reads; MFMA(a,bcur); LOADB(t+1)->bnext]; BAR;
// STAGE_A(t+2) (4 loads); vmcnt(4) (queue: A(t+1)4 oldest, B(t+1)8, A(t+2)4
// -> seals A(t+1)+B(t+1), leaves A(t+2)); sched_barrier(0) (rule 18); BAR.
// t==6: vmcnt(0) (no A(8) staged). Prologue: A(0) 4, B(0) 8, A(1) 4,
// vmcnt(4) seals A(0)+B(0).
// B frag global address: row-major Bbf, col j = jbase+wc*64+n*16+(lane&15),
// k = t*64 + ks*32 + (lane>>4)*8 -> 16B/lane, 16 cache lines/wave-instr.
// XCD map: XCD c owns bi in [8c,8c+8); 8x8 windows keep co-resident working
// set L2-resident (R9-validated: FETCH 136->37MB).
// ---------------------------------------------------------------------------
__global__ __launch_bounds__(256, 2) void gemm_cost_kernel(
    const ushort* __restrict__ Abf, const ushort* __restrict__ Bbf,
    const float2* __restrict__ idat, const float* __restrict__ exsq,
    float* __restrict__ partials) {
    __shared__ __align__(16) ushort sA[2][8192];  // 2 x 16 KB
    __shared__ float redbuf[4];

    // XCD-aware window mapping (bijective over 64x64 tiles)
    int bid0 = blockIdx.x;
    int c = bid0 & 7;            // assumed XCD id
    int sq = bid0 >> 3;          // 0..511 within XCD
    int win = sq >> 6;           // 0..7  bj window
    int pos = sq & 63;           // 0..63 within 8x8 window
    int bi = c * 8 + (pos & 7);
    int bj = win * 8 + (pos >> 3);
    int bid = bi * 64 + bj;      // bijective, for partials
    int ibase = bi * 128, jbase = bj * 128;
    int tid = threadIdx.x, lane = tid & 63, w = tid >> 6;
    int wr = w >> 1, wc = w & 1;

    // A staging per-thread constants
    int r = tid >> 3;            // 0..31
    int pc = tid & 7;            // physical 16B chunk in row
    int lc = pc ^ (r & 7);       // logical chunk (source pre-swizzle)
    const ushort* aG = Abf + (size_t)(ibase + r) * DDIM + lc * 8;
    ushort* aL = &sA[0][0] + r * 64 + pc * 8;

    // A half-tile h = 2*kt + q (q: rows 0-63 / 64-127)
    auto STAGE = [&](int h) {
        if (h >= 16) return;
        int kt = h >> 1, q = h & 1;
        const ushort* g = aG + q * (64 * DDIM) + kt * 64;
        ushort* l = aL + (kt & 1) * 8192 + q * 4096;
        gload16(g, l);
        gload16(g + 32 * DDIM, l + 2048);
    };

    // ds_read constants (read-side swizzle: chunk ^= row&7 = lane&7)
    int l15 = lane & 15;
    int pc0 = (((lane >> 4) ^ (lane & 7)) * 8);  // ushort offset, ks=0
    int pc1 = pc0 ^ 32;                          // ks=1
    int aoff = (wr * 64 + l15) * 64;

    // B global per-wave base: col = jbase + wc*64 + n*16 + l15
    const ushort* bG = Bbf + (size_t)(jbase + wc * 64 + l15) * DDIM + (lane >> 4) * 8;

    bf16x8 bA[4][2], bB[4][2];
    auto LOADB = [&](int t, bf16x8 (&b)[4][2]) {
        if (t >= 8) return;
        #pragma unroll
        for (int n = 0; n < 4; ++n)
            #pragma unroll
            for (int ks = 0; ks < 2; ++ks)
                b[n][ks] = *(const bf16x8*)(bG + (size_t)n * 16 * DDIM + t * 64 + ks * 32);
    };

    f32x4 acc[4][4] = {};

    // prologue: A(0) 4 loads, B(0) 8 loads, A(1) 4 loads; vmcnt(4) seals A0+B0
    STAGE(0); STAGE(1);
    LOADB(0, bA);
    STAGE(2); STAGE(3);
    asm volatile("s_waitcnt vmcnt(4)" ::: "memory");
    __builtin_amdgcn_sched_barrier(0);
    BAR();

    #pragma unroll
    for (int t = 0; t < 8; ++t) {
        const ushort* pA = &sA[t & 1][0];
        bf16x8 (&bcur)[4][2] = (t & 1) ? bB : bA;
        bf16x8 (&bnxt)[4][2] = (t & 1) ? bA : bB;
        bf16x8 a[4][2];

        #pragma unroll
        for (int m = 0; m < 4; ++m) {
            a[m][0] = *(const bf16x8*)(pA + aoff + m * 1024 + pc0);
            a[m][1] = *(const bf16x8*)(pA + aoff + m * 1024 + pc1);
        }
        __builtin_amdgcn_s_setprio(1);
        #pragma unroll
        for (int m = 0; m < 4; ++m)
            #pragma unroll
            for (int n = 0; n < 4; ++n) {
                acc[m][n] = __builtin_amdgcn_mfma_f32_16x16x32_bf16(a[m][0], bcur[n][0], acc[m][n], 0, 0, 0);
                acc[m][n] = __builtin_amdgcn_mfma_f32_16x16x32_bf16(a[m][1], bcur[n][1], acc[m][n], 0, 0, 0);
            }
        __builtin_amdgcn_s_setprio(0);
        LOADB(t + 1, bnxt);          // B(t+1) -> regs (8 VMEM, pre-barrier)

        BAR();                        // this tile's a-reads all consumed
        STAGE(2 * (t + 2));           // A(t+2) -> sA[t&1] (4 VMEM)
        STAGE(2 * (t + 2) + 1);
        if (t < 6)       asm volatile("s_waitcnt vmcnt(4)" ::: "memory");
        else if (t == 6) asm volatile("s_waitcnt vmcnt(0)" ::: "memory");
        __builtin_amdgcn_sched_barrier(0);
        BAR();                        // block-wide seal of A(t+1)
    }

    // epilogue: cost = max(idat.y - sqrt(max(idat.x + exsq[j] - 2*dot, 0)), 0)
    // C/D layout: col = lane&15, row = (lane>>4)*4 + reg
    float jt[4];
    #pragma unroll
    for (int n = 0; n < 4; ++n) jt[n] = exsq[jbase + wc * 64 + n * 16 + l15];
    int r0 = (lane >> 4) * 4;
    float lsum = 0.f;
    #pragma unroll
    for (int m = 0; m < 4; ++m) {
        #pragma unroll
        for (int rg = 0; rg < 4; ++rg) {
            int i = ibase + wr * 64 + m * 16 + r0 + rg;
            float2 id = idat[i];
            #pragma unroll
            for (int n = 0; n < 4; ++n) {
                float d2 = fmaxf(id.x + jt[n] - 2.0f * acc[m][n][rg], 0.0f);
                lsum += fmaxf(id.y - sqrtf(d2), 0.0f);
            }
        }
    }
    #pragma unroll
    for (int off = 32; off > 0; off >>= 1) lsum += __shfl_down(lsum, off);
    if (lane == 0) redbuf[w] = lsum;
    __syncthreads();
    if (tid == 0) partials[bid] = redbuf[0] + redbuf[1] + redbuf[2] + redbuf[3];
}

// ---------------------------------------------------------------------------
// deterministic final reduce: 4096 partials -> mean
// ---------------------------------------------------------------------------
__global__ __launch_bounds__(256) void finalize_kernel(
    const float* __restrict__ partials, float* __restrict__ out) {
    float acc = 0.f;
    for (int t = threadIdx.x; t < 4096; t += 256) acc += partials[t];
    #pragma unroll
    for (int off = 32; off > 0; off >>= 1) acc += __shfl_down(acc, off);
    __shared__ float sred[4];
    int lane = threadIdx.x & 63, w = threadIdx.x >> 6;
    if (lane == 0) sred[w] = acc;
    __syncthreads();
    if (threadIdx.x == 0) {
        float total = sred[0] + sred[1] + sred[2] + sred[3];
        out[0] = total * (1.0f / (8192.0f * 8192.0f));  // exact pow2 scale
    }
}

extern "C" void kernel_launch(void* const* d_in, const int* in_sizes, int n_in,
                              void* d_out, int out_size, void* d_ws, size_t ws_size,
                              hipStream_t stream) {
    const float* im = (const float*)d_in[0];
    const float* s  = (const float*)d_in[1];
    const float* ex = (const float*)d_in[2];

    // workspace layout (~16.9 MB)
    char* ws = (char*)d_ws;
    ushort* Abf   = (ushort*)(ws);                       // 8 MB
    ushort* Bbf   = (ushort*)(ws + 8388608);             // 8 MB
    float2* idat  = (float2*)(ws + 16777216);            // 64 KB
    float*  exsq  = (float*)(ws + 16842752);             // 32 KB
    float*  parts = (float*)(ws + 16875520);             // 16 KB

    prep_kernel<<<2 * NROW, 256, 0, stream>>>(im, s, ex, Abf, Bbf, idat, exsq);
    gemm_cost_kernel<<<(NROW / 128) * (NROW / 128), 256, 0, stream>>>(Abf, Bbf, idat, exsq, parts);
    finalize_kernel<<<1, 256, 0, stream>>>(parts, (float*)d_out);
}

// Round 16
// 169.891 us; speedup vs baseline: 1.1163x; 1.1163x over previous
//
#include <hip/hip_runtime.h>
#include <hip/hip_bf16.h>

#define NROW 8192
#define DDIM 512
#define MARGIN 0.2f

typedef __bf16 bf16x8 __attribute__((ext_vector_type(8)));
typedef float f32x4 __attribute__((ext_vector_type(4)));

__device__ __forceinline__ void gload16(const void* g, void* l) {
    __builtin_amdgcn_global_load_lds(
        (const __attribute__((address_space(1))) void*)g,
        (__attribute__((address_space(3))) void*)l, 16, 0, 0);
}

#define BAR() __builtin_amdgcn_s_barrier()

// ---------------------------------------------------------------------------
// prep: blocks 0..N-1 handle im (convert + idat={||im||^2, MARGIN+||im-s||}),
//       N..2N-1 handle ex (convert + ||ex||^2)
// ---------------------------------------------------------------------------
__global__ __launch_bounds__(256) void prep_kernel(
    const float* __restrict__ im, const float* __restrict__ s,
    const float* __restrict__ ex,
    ushort* __restrict__ Abf, ushort* __restrict__ Bbf,
    float2* __restrict__ idat, float* __restrict__ exsq) {
    int b = blockIdx.x;
    bool isim = b < NROW;
    int row = isim ? b : b - NROW;
    const float* src = isim ? im : ex;
    ushort* dst = isim ? Abf : Bbf;
    int tid = threadIdx.x;

    float2 v = ((const float2*)(src + (size_t)row * DDIM))[tid];
    __hip_bfloat16 hx = __float2bfloat16(v.x);
    __hip_bfloat16 hy = __float2bfloat16(v.y);
    unsigned packed = (unsigned)*(const ushort*)&hx | ((unsigned)*(const ushort*)&hy << 16);
    ((unsigned*)(dst + (size_t)row * DDIM))[tid] = packed;

    float ssq = v.x * v.x + v.y * v.y;
    float dsq = 0.f;
    if (isim) {
        float2 sv = ((const float2*)(s + (size_t)row * DDIM))[tid];
        float dx = v.x - sv.x, dy = v.y - sv.y;
        dsq = dx * dx + dy * dy;
    }
    #pragma unroll
    for (int off = 32; off > 0; off >>= 1) {
        ssq += __shfl_down(ssq, off);
        dsq += __shfl_down(dsq, off);
    }
    __shared__ float sred[8];
    int lane = tid & 63, w = tid >> 6;
    if (lane == 0) { sred[w] = ssq; sred[4 + w] = dsq; }
    __syncthreads();
    if (tid == 0) {
        float S = sred[0] + sred[1] + sred[2] + sred[3];
        float Dd = sred[4] + sred[5] + sred[6] + sred[7];
        if (isim) idat[row] = make_float2(S, MARGIN + sqrtf(Dd));
        else      exsq[row] = S;
    }
}

// ---------------------------------------------------------------------------
// 128x128 GEMM + fused epilogue. 4 waves (2x2), BK=64, A+B in LDS.
// KEY CHANGE vs R14/R15: INTRA-WAVE FRAGMENT DOUBLE-BUFFER. Iter t issues
// the 16 ds_reads for tile t+1's fragments (into the other register set)
// BEFORE the 32 MFMAs of tile t (whose operands are already in regs from
// iter t-1) -> ds_read execution overlaps MFMA execution within each wave,
// no dependency, no reliance on TLP. (R15 evidence: B-from-global regressed
// -- L2 latency in the boundary chain; R12: MFMA skeleton at full rate;
// all-LDS lockstep schedules pin at 20-24% because reads(t) -> MFMA(t)
// serialize per wave.)
// Register pipeline needs tile t+1 SEALED at iter t start -> LDS 3-deep:
// sAB[3] regions of 32KB (A rows 0-127 at 0, B at +8192 ushorts). 96KB ->
// 1 block/CU, 4 waves (1/SIMD), full 256-VGPR budget (acc 64 + frags 128).
// Ledger: prologue stages tiles 0,1,2 (24 loads), vmcnt(8) seals 0,1; BAR;
// read frags(0). Iter t: reads frags(t+1) from buf[(t+1)%3] (sealed by
// invariant: end of iter t-1 sealed tile t+1); MFMA(t); BAR (buf[t%3]
// consumed block-wide); STAGE(t+3) -> buf[t%3]; t<5: vmcnt(8) seals t+2,
// t==5: vmcnt(0) seals 7; sched_barrier(0); BAR.
// Swizzle (validated R9-R14): phys chunk = logical ^ (row&7), both sides;
// staging rows r+32k share r&7; read rows wr*64+m*16+l15 -> row&7 = lane&7.
// XCD map (validated R9): XCD c owns bi in [8c,8c+8); 8x8 bj windows.
// ---------------------------------------------------------------------------
__global__ __launch_bounds__(256, 1) void gemm_cost_kernel(
    const ushort* __restrict__ Abf, const ushort* __restrict__ Bbf,
    const float2* __restrict__ idat, const float* __restrict__ exsq,
    float* __restrict__ partials) {
    __shared__ __align__(16) ushort sAB[3][16384];  // 3 x 32 KB (A | B)
    __shared__ float redbuf[4];

    // XCD-aware window mapping (bijective over 64x64 tiles)
    int bid0 = blockIdx.x;
    int c = bid0 & 7;            // assumed XCD id
    int sq = bid0 >> 3;          // 0..511 within XCD
    int win = sq >> 6;           // 0..7  bj window
    int pos = sq & 63;           // 0..63 within 8x8 window
    int bi = c * 8 + (pos & 7);
    int bj = win * 8 + (pos >> 3);
    int bid = bi * 64 + bj;      // bijective, for partials
    int ibase = bi * 128, jbase = bj * 128;
    int tid = threadIdx.x, lane = tid & 63, w = tid >> 6;
    int wr = w >> 1, wc = w & 1;

    // staging per-thread constants: r = tid>>3 covers rows r, r+32, r+64, r+96
    int r = tid >> 3;            // 0..31
    int pc = tid & 7;            // physical 16B chunk in row
    int lc = pc ^ (r & 7);       // logical chunk (source pre-swizzle)
    const ushort* aG = Abf + (size_t)(ibase + r) * DDIM + lc * 8;
    const ushort* bG = Bbf + (size_t)(jbase + r) * DDIM + lc * 8;
    ushort* lL = &sAB[0][0] + r * 64 + pc * 8;

    // full tile kt: A 4 calls + B 4 calls (8 x gload16 = 8 VMEM/thread-group)
    auto STAGE = [&](int kt) {
        if (kt >= 8) return;
        ushort* base = lL + (kt % 3) * 16384;
        const ushort* ga = aG + kt * 64;
        const ushort* gb = bG + kt * 64;
        #pragma unroll
        for (int q = 0; q < 4; ++q)
            gload16(ga + q * (32 * DDIM), base + q * 2048);
        #pragma unroll
        for (int q = 0; q < 4; ++q)
            gload16(gb + q * (32 * DDIM), base + 8192 + q * 2048);
    };

    // ds_read constants (read-side swizzle: chunk ^= row&7 = lane&7)
    int l15 = lane & 15;
    int pc0 = (((lane >> 4) ^ (lane & 7)) * 8);  // ushort offset, ks=0
    int pc1 = pc0 ^ 32;                          // ks=1
    int aoff = (wr * 64 + l15) * 64;
    int boff = 8192 + (wc * 64 + l15) * 64;

    f32x4 acc[4][4] = {};
    bf16x8 aR0[4][2], aR1[4][2], bR0[4][2], bR1[4][2];

    // prologue: stage tiles 0,1,2 (24 loads); vmcnt(8) seals tiles 0,1
    STAGE(0); STAGE(1); STAGE(2);
    asm volatile("s_waitcnt vmcnt(8)" ::: "memory");
    __builtin_amdgcn_sched_barrier(0);
    BAR();
    {   // read frags(0) into set 0
        const ushort* p0 = &sAB[0][0];
        #pragma unroll
        for (int m = 0; m < 4; ++m) {
            aR0[m][0] = *(const bf16x8*)(p0 + aoff + m * 1024 + pc0);
            aR0[m][1] = *(const bf16x8*)(p0 + aoff + m * 1024 + pc1);
        }
        #pragma unroll
        for (int n = 0; n < 4; ++n) {
            bR0[n][0] = *(const bf16x8*)(p0 + boff + n * 1024 + pc0);
            bR0[n][1] = *(const bf16x8*)(p0 + boff + n * 1024 + pc1);
        }
    }

    #pragma unroll
    for (int t = 0; t < 8; ++t) {
        bf16x8 (&ac)[4][2] = (t & 1) ? aR1 : aR0;  // current (compile-time)
        bf16x8 (&bc)[4][2] = (t & 1) ? bR1 : bR0;
        bf16x8 (&an)[4][2] = (t & 1) ? aR0 : aR1;  // next
        bf16x8 (&bn)[4][2] = (t & 1) ? bR0 : bR1;

        // issue reads for tile t+1 (no dep on MFMA(t) -> overlaps execution)
        if (t < 7) {
            const ushort* pN = &sAB[0][0] + ((t + 1) % 3) * 16384;
            #pragma unroll
            for (int m = 0; m < 4; ++m) {
                an[m][0] = *(const bf16x8*)(pN + aoff + m * 1024 + pc0);
                an[m][1] = *(const bf16x8*)(pN + aoff + m * 1024 + pc1);
            }
            #pragma unroll
            for (int n = 0; n < 4; ++n) {
                bn[n][0] = *(const bf16x8*)(pN + boff + n * 1024 + pc0);
                bn[n][1] = *(const bf16x8*)(pN + boff + n * 1024 + pc1);
            }
        }

        __builtin_amdgcn_s_setprio(1);
        #pragma unroll
        for (int m = 0; m < 4; ++m)
            #pragma unroll
            for (int n = 0; n < 4; ++n) {
                acc[m][n] = __builtin_amdgcn_mfma_f32_16x16x32_bf16(ac[m][0], bc[n][0], acc[m][n], 0, 0, 0);
                acc[m][n] = __builtin_amdgcn_mfma_f32_16x16x32_bf16(ac[m][1], bc[n][1], acc[m][n], 0, 0, 0);
            }
        __builtin_amdgcn_s_setprio(0);

        BAR();                        // buf[t%3] fully consumed block-wide
        STAGE(t + 3);                 // overwrite buf[t%3] with tile t+3
        if (t < 5)       asm volatile("s_waitcnt vmcnt(8)" ::: "memory");
        else if (t == 5) asm volatile("s_waitcnt vmcnt(0)" ::: "memory");
        __builtin_amdgcn_sched_barrier(0);
        BAR();                        // block-wide seal of tile t+2
    }

    // epilogue: cost = max(idat.y - sqrt(max(idat.x + exsq[j] - 2*dot, 0)), 0)
    // C/D layout: col = lane&15, row = (lane>>4)*4 + reg
    float jt[4];
    #pragma unroll
    for (int n = 0; n < 4; ++n) jt[n] = exsq[jbase + wc * 64 + n * 16 + l15];
    int r0 = (lane >> 4) * 4;
    float lsum = 0.f;
    #pragma unroll
    for (int m = 0; m < 4; ++m) {
        #pragma unroll
        for (int rg = 0; rg < 4; ++rg) {
            int i = ibase + wr * 64 + m * 16 + r0 + rg;
            float2 id = idat[i];
            #pragma unroll
            for (int n = 0; n < 4; ++n) {
                float d2 = fmaxf(id.x + jt[n] - 2.0f * acc[m][n][rg], 0.0f);
                lsum += fmaxf(id.y - sqrtf(d2), 0.0f);
            }
        }
    }
    #pragma unroll
    for (int off = 32; off > 0; off >>= 1) lsum += __shfl_down(lsum, off);
    if (lane == 0) redbuf[w] = lsum;
    __syncthreads();
    if (tid == 0) partials[bid] = redbuf[0] + redbuf[1] + redbuf[2] + redbuf[3];
}

// ---------------------------------------------------------------------------
// deterministic final reduce: 4096 partials -> mean
// ---------------------------------------------------------------------------
__global__ __launch_bounds__(256) void finalize_kernel(
    const float* __restrict__ partials, float* __restrict__ out) {
    float acc = 0.f;
    for (int t = threadIdx.x; t < 4096; t += 256) acc += partials[t];
    #pragma unroll
    for (int off = 32; off > 0; off >>= 1) acc += __shfl_down(acc, off);
    __shared__ float sred[4];
    int lane = threadIdx.x & 63, w = threadIdx.x >> 6;
    if (lane == 0) sred[w] = acc;
    __syncthreads();
    if (threadIdx.x == 0) {
        float total = sred[0] + sred[1] + sred[2] + sred[3];
        out[0] = total * (1.0f / (8192.0f * 8192.0f));  // exact pow2 scale
    }
}

extern "C" void kernel_launch(void* const* d_in, const int* in_sizes, int n_in,
                              void* d_out, int out_size, void* d_ws, size_t ws_size,
                              hipStream_t stream) {
    const float* im = (const float*)d_in[0];
    const float* s  = (const float*)d_in[1];
    const float* ex = (const float*)d_in[2];

    // workspace layout (~16.9 MB)
    char* ws = (char*)d_ws;
    ushort* Abf   = (ushort*)(ws);                       // 8 MB
    ushort* Bbf   = (ushort*)(ws + 8388608);             // 8 MB
    float2* idat  = (float2*)(ws + 16777216);            // 64 KB
    float*  exsq  = (float*)(ws + 16842752);             // 32 KB
    float*  parts = (float*)(ws + 16875520);             // 16 KB

    prep_kernel<<<2 * NROW, 256, 0, stream>>>(im, s, ex, Abf, Bbf, idat, exsq);
    gemm_cost_kernel<<<(NROW / 128) * (NROW / 128), 256, 0, stream>>>(Abf, Bbf, idat, exsq, parts);
    finalize_kernel<<<1, 256, 0, stream>>>(parts, (float*)d_out);
}

// Round 17
// 110.326 us; speedup vs baseline: 1.7190x; 1.5399x over previous
//
#include <hip/hip_runtime.h>
#include <hip/hip_bf16.h>

#define NROW 8192
#define DDIM 512
#define MARGIN 0.2f

typedef __bf16 bf16x8 __attribute__((ext_vector_type(8)));
typedef float f32x4 __attribute__((ext_vector_type(4)));

__device__ __forceinline__ void gload16(const void* g, void* l) {
    __builtin_amdgcn_global_load_lds(
        (const __attribute__((address_space(1))) void*)g,
        (__attribute__((address_space(3))) void*)l, 16, 0, 0);
}

#define BAR() __builtin_amdgcn_s_barrier()

// ---------------------------------------------------------------------------
// prep: blocks 0..N-1 handle im (convert + idat={||im||^2, MARGIN+||im-s||}),
//       N..2N-1 handle ex (convert + ||ex||^2)
// ---------------------------------------------------------------------------
__global__ __launch_bounds__(256) void prep_kernel(
    const float* __restrict__ im, const float* __restrict__ s,
    const float* __restrict__ ex,
    ushort* __restrict__ Abf, ushort* __restrict__ Bbf,
    float2* __restrict__ idat, float* __restrict__ exsq) {
    int b = blockIdx.x;
    bool isim = b < NROW;
    int row = isim ? b : b - NROW;
    const float* src = isim ? im : ex;
    ushort* dst = isim ? Abf : Bbf;
    int tid = threadIdx.x;

    float2 v = ((const float2*)(src + (size_t)row * DDIM))[tid];
    __hip_bfloat16 hx = __float2bfloat16(v.x);
    __hip_bfloat16 hy = __float2bfloat16(v.y);
    unsigned packed = (unsigned)*(const ushort*)&hx | ((unsigned)*(const ushort*)&hy << 16);
    ((unsigned*)(dst + (size_t)row * DDIM))[tid] = packed;

    float ssq = v.x * v.x + v.y * v.y;
    float dsq = 0.f;
    if (isim) {
        float2 sv = ((const float2*)(s + (size_t)row * DDIM))[tid];
        float dx = v.x - sv.x, dy = v.y - sv.y;
        dsq = dx * dx + dy * dy;
    }
    #pragma unroll
    for (int off = 32; off > 0; off >>= 1) {
        ssq += __shfl_down(ssq, off);
        dsq += __shfl_down(dsq, off);
    }
    __shared__ float sred[8];
    int lane = tid & 63, w = tid >> 6;
    if (lane == 0) { sred[w] = ssq; sred[4 + w] = dsq; }
    __syncthreads();
    if (tid == 0) {
        float S = sred[0] + sred[1] + sred[2] + sred[3];
        float Dd = sred[4] + sred[5] + sred[6] + sred[7];
        if (isim) idat[row] = make_float2(S, MARGIN + sqrtf(Dd));
        else      exsq[row] = S;
    }
}

// ---------------------------------------------------------------------------
// 128x128 GEMM + fused epilogue. 4 waves (2x2), BK=32, dbuf LDS = 32.2 KB.
// GOAL: 4+ independent co-resident blocks/CU (m97 ran at ~3 blocks/CU and
// the guide credits cross-block implicit overlap for hiding stage/LDS time;
// all my 1-2 block configs pinned at 20-24% MfmaUtil; R12 proved the MFMA
// skeleton itself runs at full rate). launch_bounds(256,4) caps VGPR at 128.
// Diagnostic readout: OccupancyPercent >=33% -> mechanism engaged.
// LDS rows 64B (4 chunks), XOR swizzle phys = logical ^ (row&3) both sides;
// worst case 2-way on 8-lane b128 groups = free (m136). Staging dest linear
// (lane byte = tid*16, gload_lds-compliant); source pre-swizzled.
// Ledger (R14-validated pattern, BK32): STAGE(kt) = 4 gload (A2+B2).
// Prologue: STAGE(0),STAGE(1), vmcnt(4) seals tile 0, BAR. Iter t (0..15):
// read frags(t) from buf[t&1] (8 ds_read_b128), 16 MFMA (compiler lgkm
// waits), BAR (reads consumed block-wide), STAGE(t+2) -> buf[t&1],
// vmcnt(4) seals t+1 (t<14; vmcnt(0) at t==14), sched_barrier(0), BAR.
// XCD map (R9-validated, FETCH 136->37MB): XCD c owns bi in [8c,8c+8);
// 8x8 bj windows keep co-resident set < 4MB L2.
// ---------------------------------------------------------------------------
__global__ __launch_bounds__(256, 4) void gemm_cost_kernel(
    const ushort* __restrict__ Abf, const ushort* __restrict__ Bbf,
    const float2* __restrict__ idat, const float* __restrict__ exsq,
    float* __restrict__ partials) {
    __shared__ __align__(16) ushort sA[2][4096];  // 2 x 8 KB
    __shared__ __align__(16) ushort sB[2][4096];  // 2 x 8 KB
    __shared__ float redbuf[4];

    // XCD-aware window mapping (bijective over 64x64 tiles)
    int bid0 = blockIdx.x;
    int c = bid0 & 7;            // assumed XCD id
    int sq = bid0 >> 3;          // 0..511 within XCD
    int win = sq >> 6;           // 0..7  bj window
    int pos = sq & 63;           // 0..63 within 8x8 window
    int bi = c * 8 + (pos & 7);
    int bj = win * 8 + (pos >> 3);
    int bid = bi * 64 + bj;      // bijective, for partials
    int ibase = bi * 128, jbase = bj * 128;
    int tid = threadIdx.x, lane = tid & 63, w = tid >> 6;
    int wr = w >> 1, wc = w & 1;

    // staging per-thread constants: r covers rows r and r+64 (same r&3)
    int r = tid >> 2;            // 0..63
    int pc = tid & 3;            // physical 16B chunk in 64B row
    int lc = pc ^ (r & 3);       // logical chunk (source pre-swizzle)
    const ushort* aG = Abf + (size_t)(ibase + r) * DDIM + lc * 8;
    const ushort* bG = Bbf + (size_t)(jbase + r) * DDIM + lc * 8;
    ushort* aL = &sA[0][0] + r * 32 + pc * 8;
    ushort* bL = &sB[0][0] + r * 32 + pc * 8;

    auto STAGE = [&](int kt) {
        if (kt >= 16) return;
        const ushort* ga = aG + kt * 32;
        const ushort* gb = bG + kt * 32;
        ushort* la = aL + (kt & 1) * 4096;
        ushort* lb = bL + (kt & 1) * 4096;
        gload16(ga, la);
        gload16(ga + 64 * DDIM, la + 2048);
        gload16(gb, lb);
        gload16(gb + 64 * DDIM, lb + 2048);
    };

    // ds_read constants (read-side swizzle: chunk ^= row&3 = lane&3)
    int l15 = lane & 15;
    int koffb = (((lane >> 4) ^ (lane & 3)) * 8);  // ushort offset in row
    int aoff = (wr * 64 + l15) * 32;
    int boff = (wc * 64 + l15) * 32;

    f32x4 acc[4][4] = {};

    // prologue: tiles 0,1 staged (8 loads); vmcnt(4) seals tile 0
    STAGE(0); STAGE(1);
    asm volatile("s_waitcnt vmcnt(4)" ::: "memory");
    __builtin_amdgcn_sched_barrier(0);
    BAR();

    #pragma unroll
    for (int t = 0; t < 16; ++t) {
        const ushort* pA = &sA[t & 1][0];
        const ushort* pB = &sB[t & 1][0];
        bf16x8 a[4], b[4];

        #pragma unroll
        for (int m = 0; m < 4; ++m)
            a[m] = *(const bf16x8*)(pA + aoff + m * 512 + koffb);
        #pragma unroll
        for (int n = 0; n < 4; ++n)
            b[n] = *(const bf16x8*)(pB + boff + n * 512 + koffb);
        #pragma unroll
        for (int m = 0; m < 4; ++m)
            #pragma unroll
            for (int n = 0; n < 4; ++n)
                acc[m][n] = __builtin_amdgcn_mfma_f32_16x16x32_bf16(a[m], b[n], acc[m][n], 0, 0, 0);

        BAR();                        // this tile's reads consumed block-wide
        STAGE(t + 2);                 // overwrite buf[t&1] with tile t+2
        if (t < 14)       asm volatile("s_waitcnt vmcnt(4)" ::: "memory");
        else if (t == 14) asm volatile("s_waitcnt vmcnt(0)" ::: "memory");
        __builtin_amdgcn_sched_barrier(0);
        BAR();                        // block-wide seal of tile t+1
    }

    // epilogue: cost = max(idat.y - sqrt(max(idat.x + exsq[j] - 2*dot, 0)), 0)
    // C/D layout: col = lane&15, row = (lane>>4)*4 + reg
    float jt[4];
    #pragma unroll
    for (int n = 0; n < 4; ++n) jt[n] = exsq[jbase + wc * 64 + n * 16 + l15];
    int r0 = (lane >> 4) * 4;
    float lsum = 0.f;
    #pragma unroll
    for (int m = 0; m < 4; ++m) {
        #pragma unroll
        for (int rg = 0; rg < 4; ++rg) {
            int i = ibase + wr * 64 + m * 16 + r0 + rg;
            float2 id = idat[i];
            #pragma unroll
            for (int n = 0; n < 4; ++n) {
                float d2 = fmaxf(id.x + jt[n] - 2.0f * acc[m][n][rg], 0.0f);
                lsum += fmaxf(id.y - sqrtf(d2), 0.0f);
            }
        }
    }
    #pragma unroll
    for (int off = 32; off > 0; off >>= 1) lsum += __shfl_down(lsum, off);
    if (lane == 0) redbuf[w] = lsum;
    __syncthreads();
    if (tid == 0) partials[bid] = redbuf[0] + redbuf[1] + redbuf[2] + redbuf[3];
}

// ---------------------------------------------------------------------------
// deterministic final reduce: 4096 partials -> mean
// ---------------------------------------------------------------------------
__global__ __launch_bounds__(256) void finalize_kernel(
    const float* __restrict__ partials, float* __restrict__ out) {
    float acc = 0.f;
    for (int t = threadIdx.x; t < 4096; t += 256) acc += partials[t];
    #pragma unroll
    for (int off = 32; off > 0; off >>= 1) acc += __shfl_down(acc, off);
    __shared__ float sred[4];
    int lane = threadIdx.x & 63, w = threadIdx.x >> 6;
    if (lane == 0) sred[w] = acc;
    __syncthreads();
    if (threadIdx.x == 0) {
        float total = sred[0] + sred[1] + sred[2] + sred[3];
        out[0] = total * (1.0f / (8192.0f * 8192.0f));  // exact pow2 scale
    }
}

extern "C" void kernel_launch(void* const* d_in, const int* in_sizes, int n_in,
                              void* d_out, int out_size, void* d_ws, size_t ws_size,
                              hipStream_t stream) {
    const float* im = (const float*)d_in[0];
    const float* s  = (const float*)d_in[1];
    const float* ex = (const float*)d_in[2];

    // workspace layout (~16.9 MB)
    char* ws = (char*)d_ws;
    ushort* Abf   = (ushort*)(ws);                       // 8 MB
    ushort* Bbf   = (ushort*)(ws + 8388608);             // 8 MB
    float2* idat  = (float2*)(ws + 16777216);            // 64 KB
    float*  exsq  = (float*)(ws + 16842752);             // 32 KB
    float*  parts = (float*)(ws + 16875520);             // 16 KB

    prep_kernel<<<2 * NROW, 256, 0, stream>>>(im, s, ex, Abf, Bbf, idat, exsq);
    gemm_cost_kernel<<<(NROW / 128) * (NROW / 128), 256, 0, stream>>>(Abf, Bbf, idat, exsq, parts);
    finalize_kernel<<<1, 256, 0, stream>>>(parts, (float*)d_out);
}